// Round 1
// baseline (2230.418 us; speedup 1.0000x reference)
//
#include <hip/hip_runtime.h>

// GCN forward: 2× GCNConv (sym-norm, self-loops) + linear head.
// Pipeline: deg -> dinv -> (x@W1, agg1 init w/ self-loop) -> edge scatter (32)
//           -> (relu(agg1+b1)@W2, agg2 init) -> edge scatter (16) -> head.

#define TPB 256

__global__ void init_deg_kernel(float* __restrict__ deg, int N) {
    int i = blockIdx.x * blockDim.x + threadIdx.x;
    if (i < N) deg[i] = 1.0f;  // self-loop
}

__global__ void count_deg_kernel(const int* __restrict__ dst, float* __restrict__ deg, int E) {
    int e = blockIdx.x * blockDim.x + threadIdx.x;
    if (e < E) atomicAdd(&deg[dst[e]], 1.0f);
}

__global__ void rsqrt_kernel(float* __restrict__ deg, int N) {
    int i = blockIdx.x * blockDim.x + threadIdx.x;
    if (i < N) deg[i] = rsqrtf(fmaxf(deg[i], 1.0f));  // in-place: deg -> dinv
}

// xw = x @ W1 ; agg1 = xw * dinv^2 (self-loop message pre-seeded)
__global__ void gemm1_kernel(const float* __restrict__ x, const float* __restrict__ W1,
                             const float* __restrict__ dinv,
                             float* __restrict__ xw, float* __restrict__ agg, int N) {
    __shared__ float ws_[128 * 32];
    for (int i = threadIdx.x; i < 128 * 32; i += blockDim.x) ws_[i] = W1[i];
    __syncthreads();
    int node = blockIdx.x * blockDim.x + threadIdx.x;
    if (node >= N) return;
    float acc[32];
#pragma unroll
    for (int j = 0; j < 32; ++j) acc[j] = 0.0f;
    const float4* xr = (const float4*)(x + (size_t)node * 128);
#pragma unroll 4
    for (int k4 = 0; k4 < 32; ++k4) {
        float4 xv = xr[k4];
        const float* wk = ws_ + k4 * 128;  // 4 consecutive k-rows of 32
#pragma unroll
        for (int j4 = 0; j4 < 8; ++j4) {
            float4 w0 = *(const float4*)(wk + j4 * 4);
            float4 w1 = *(const float4*)(wk + 32 + j4 * 4);
            float4 w2 = *(const float4*)(wk + 64 + j4 * 4);
            float4 w3 = *(const float4*)(wk + 96 + j4 * 4);
            acc[j4 * 4 + 0] += xv.x * w0.x + xv.y * w1.x + xv.z * w2.x + xv.w * w3.x;
            acc[j4 * 4 + 1] += xv.x * w0.y + xv.y * w1.y + xv.z * w2.y + xv.w * w3.y;
            acc[j4 * 4 + 2] += xv.x * w0.z + xv.y * w1.z + xv.z * w2.z + xv.w * w3.z;
            acc[j4 * 4 + 3] += xv.x * w0.w + xv.y * w1.w + xv.z * w2.w + xv.w * w3.w;
        }
    }
    float d = dinv[node];
    float d2 = d * d;
    float4* xwp = (float4*)(xw + (size_t)node * 32);
    float4* agp = (float4*)(agg + (size_t)node * 32);
#pragma unroll
    for (int j4 = 0; j4 < 8; ++j4) {
        float4 v = make_float4(acc[j4 * 4 + 0], acc[j4 * 4 + 1], acc[j4 * 4 + 2], acc[j4 * 4 + 3]);
        xwp[j4] = v;
        agp[j4] = make_float4(v.x * d2, v.y * d2, v.z * d2, v.w * d2);
    }
}

// 8 lanes per edge, each lane: float4 gather + 4 atomic adds (32 comps)
__global__ void edge_agg32_kernel(const int* __restrict__ src, const int* __restrict__ dst,
                                  const float* __restrict__ dinv, const float* __restrict__ xw,
                                  float* __restrict__ agg, int E) {
    unsigned tid = blockIdx.x * blockDim.x + threadIdx.x;
    unsigned e = tid >> 3;
    if (e >= (unsigned)E) return;
    int c = (tid & 7) * 4;
    int s = src[e], d = dst[e];
    float nrm = dinv[s] * dinv[d];
    float4 v = *(const float4*)(xw + (size_t)s * 32 + c);
    float* out = agg + (size_t)d * 32 + c;
    atomicAdd(out + 0, v.x * nrm);
    atomicAdd(out + 1, v.y * nrm);
    atomicAdd(out + 2, v.z * nrm);
    atomicAdd(out + 3, v.w * nrm);
}

// h2w = relu(agg1 + b1) @ W2 ; agg2 = h2w * dinv^2
__global__ void gemm2_kernel(const float* __restrict__ agg1, const float* __restrict__ W2,
                             const float* __restrict__ b1, const float* __restrict__ dinv,
                             float* __restrict__ h2w, float* __restrict__ agg2, int N) {
    __shared__ float ws_[32 * 16];
    __shared__ float bs_[32];
    for (int i = threadIdx.x; i < 32 * 16; i += blockDim.x) ws_[i] = W2[i];
    if (threadIdx.x < 32) bs_[threadIdx.x] = b1[threadIdx.x];
    __syncthreads();
    int node = blockIdx.x * blockDim.x + threadIdx.x;
    if (node >= N) return;
    float h[32];
    const float4* ar = (const float4*)(agg1 + (size_t)node * 32);
#pragma unroll
    for (int k4 = 0; k4 < 8; ++k4) {
        float4 v = ar[k4];
        h[k4 * 4 + 0] = fmaxf(v.x + bs_[k4 * 4 + 0], 0.0f);
        h[k4 * 4 + 1] = fmaxf(v.y + bs_[k4 * 4 + 1], 0.0f);
        h[k4 * 4 + 2] = fmaxf(v.z + bs_[k4 * 4 + 2], 0.0f);
        h[k4 * 4 + 3] = fmaxf(v.w + bs_[k4 * 4 + 3], 0.0f);
    }
    float acc[16];
#pragma unroll
    for (int j = 0; j < 16; ++j) acc[j] = 0.0f;
#pragma unroll
    for (int k = 0; k < 32; ++k) {
        float hv = h[k];
#pragma unroll
        for (int j4 = 0; j4 < 4; ++j4) {
            float4 w = *(const float4*)(ws_ + k * 16 + j4 * 4);
            acc[j4 * 4 + 0] += hv * w.x;
            acc[j4 * 4 + 1] += hv * w.y;
            acc[j4 * 4 + 2] += hv * w.z;
            acc[j4 * 4 + 3] += hv * w.w;
        }
    }
    float d = dinv[node];
    float d2 = d * d;
    float4* hp = (float4*)(h2w + (size_t)node * 16);
    float4* ap = (float4*)(agg2 + (size_t)node * 16);
#pragma unroll
    for (int j4 = 0; j4 < 4; ++j4) {
        float4 v = make_float4(acc[j4 * 4 + 0], acc[j4 * 4 + 1], acc[j4 * 4 + 2], acc[j4 * 4 + 3]);
        hp[j4] = v;
        ap[j4] = make_float4(v.x * d2, v.y * d2, v.z * d2, v.w * d2);
    }
}

// 4 lanes per edge, each lane: float4 gather + 4 atomic adds (16 comps)
__global__ void edge_agg16_kernel(const int* __restrict__ src, const int* __restrict__ dst,
                                  const float* __restrict__ dinv, const float* __restrict__ h2w,
                                  float* __restrict__ agg, int E) {
    unsigned tid = blockIdx.x * blockDim.x + threadIdx.x;
    unsigned e = tid >> 2;
    if (e >= (unsigned)E) return;
    int c = (tid & 3) * 4;
    int s = src[e], d = dst[e];
    float nrm = dinv[s] * dinv[d];
    float4 v = *(const float4*)(h2w + (size_t)s * 16 + c);
    float* out = agg + (size_t)d * 16 + c;
    atomicAdd(out + 0, v.x * nrm);
    atomicAdd(out + 1, v.y * nrm);
    atomicAdd(out + 2, v.z * nrm);
    atomicAdd(out + 3, v.w * nrm);
}

// out = relu(agg2 + b2) @ Wf + bf
__global__ void final_kernel(const float* __restrict__ agg2, const float* __restrict__ b2,
                             const float* __restrict__ Wf, const float* __restrict__ bf,
                             float* __restrict__ out, int N) {
    int i = blockIdx.x * blockDim.x + threadIdx.x;
    if (i >= N) return;
    const float4* ar = (const float4*)(agg2 + (size_t)i * 16);
    float acc = bf[0];
#pragma unroll
    for (int j4 = 0; j4 < 4; ++j4) {
        float4 v = ar[j4];
        acc += fmaxf(v.x + b2[j4 * 4 + 0], 0.0f) * Wf[j4 * 4 + 0];
        acc += fmaxf(v.y + b2[j4 * 4 + 1], 0.0f) * Wf[j4 * 4 + 1];
        acc += fmaxf(v.z + b2[j4 * 4 + 2], 0.0f) * Wf[j4 * 4 + 2];
        acc += fmaxf(v.w + b2[j4 * 4 + 3], 0.0f) * Wf[j4 * 4 + 3];
    }
    out[i] = acc;
}

extern "C" void kernel_launch(void* const* d_in, const int* in_sizes, int n_in,
                              void* d_out, int out_size, void* d_ws, size_t ws_size,
                              hipStream_t stream) {
    const float* x  = (const float*)d_in[0];
    const int*   ei = (const int*)d_in[1];
    const float* W1 = (const float*)d_in[2];
    const float* b1 = (const float*)d_in[3];
    const float* W2 = (const float*)d_in[4];
    const float* b2 = (const float*)d_in[5];
    const float* Wf = (const float*)d_in[6];
    const float* bf = (const float*)d_in[7];

    int N = in_sizes[0] / 128;
    int E = in_sizes[1] / 2;
    const int* src = ei;       // edge_index[0]
    const int* dst = ei + E;   // edge_index[1]

    // Workspace layout (floats), all regions fully written before read:
    size_t Np = ((size_t)N + 3) & ~(size_t)3;  // keep float4 alignment
    float* ws   = (float*)d_ws;
    float* dinv = ws;                 // N      (deg -> dinv in place)
    float* xw   = dinv + Np;          // 32*N
    float* agg1 = xw + 32 * Np;       // 32*N
    float* h2w  = agg1 + 32 * Np;     // 16*N
    float* agg2 = h2w + 16 * Np;      // 16*N   (total ~97*N floats = 38.8 MB)
    float* out  = (float*)d_out;

    int nbN = (N + TPB - 1) / TPB;
    int nbE = (E + TPB - 1) / TPB;

    init_deg_kernel<<<nbN, TPB, 0, stream>>>(dinv, N);
    count_deg_kernel<<<nbE, TPB, 0, stream>>>(dst, dinv, E);
    rsqrt_kernel<<<nbN, TPB, 0, stream>>>(dinv, N);
    gemm1_kernel<<<nbN, TPB, 0, stream>>>(x, W1, dinv, xw, agg1, N);
    edge_agg32_kernel<<<(int)(((size_t)E * 8 + TPB - 1) / TPB), TPB, 0, stream>>>(src, dst, dinv, xw, agg1, E);
    gemm2_kernel<<<nbN, TPB, 0, stream>>>(agg1, W2, b1, dinv, h2w, agg2, N);
    edge_agg16_kernel<<<(int)(((size_t)E * 4 + TPB - 1) / TPB), TPB, 0, stream>>>(src, dst, dinv, h2w, agg2, E);
    final_kernel<<<nbN, TPB, 0, stream>>>(agg2, b2, Wf, bf, out, N);
}

// Round 3
// 758.415 us; speedup vs baseline: 2.9409x; 2.9409x over previous
//
#include <hip/hip_runtime.h>

// GCN forward via CSR-gather (no float atomics):
//   counts -> scan -> scatter(src by dst) builds CSR once;
//   gemm1 writes xwd = (x@W1)*dinv; agg1[d] = dinv[d]*(xwd[d] + sum_in xwd[s]);
//   gemm2 writes h2wd = (relu(agg1+b1)@W2)*dinv; agg2 same with 16 feats; head.

#define TPB 256

__global__ void zero_counts_kernel(int* __restrict__ counts, int N) {
    int i = blockIdx.x * blockDim.x + threadIdx.x;
    if (i < N) counts[i] = 0;
}

__global__ void count_kernel(const int* __restrict__ dst, int* __restrict__ counts, int E) {
    int e = blockIdx.x * blockDim.x + threadIdx.x;
    if (e < E) atomicAdd(&counts[dst[e]], 1);
}

// Per-block exclusive scan of counts -> offs, block sums -> bsums
__global__ void scan_block_kernel(const int* __restrict__ counts, int* __restrict__ offs,
                                  int* __restrict__ bsums, int N) {
    __shared__ int s[TPB];
    int i = blockIdx.x * TPB + threadIdx.x;
    int v = (i < N) ? counts[i] : 0;
    s[threadIdx.x] = v;
    __syncthreads();
    for (int d = 1; d < TPB; d <<= 1) {
        int t = 0;
        if ((int)threadIdx.x >= d) t = s[threadIdx.x - d];
        __syncthreads();
        s[threadIdx.x] += t;
        __syncthreads();
    }
    if (i < N) offs[i] = s[threadIdx.x] - v;  // exclusive
    if (threadIdx.x == TPB - 1) bsums[blockIdx.x] = s[TPB - 1];
}

// Single-block exclusive scan of block sums (nb <= 512)
__global__ void scan_sums_kernel(int* __restrict__ bsums, int nb) {
    __shared__ int s[512];
    int tid = threadIdx.x;
    int v = (tid < nb) ? bsums[tid] : 0;
    s[tid] = v;
    __syncthreads();
    for (int d = 1; d < 512; d <<= 1) {
        int t = 0;
        if (tid >= d) t = s[tid - d];
        __syncthreads();
        s[tid] += t;
        __syncthreads();
    }
    if (tid < nb) bsums[tid] = s[tid] - v;  // exclusive
}

// offs += scanned block sums; cursor = offs; dinv = rsqrt(counts+1)
__global__ void finalize_kernel(const int* __restrict__ counts, int* __restrict__ offs,
                                const int* __restrict__ bsums, int* __restrict__ cursor,
                                float* __restrict__ dinv, int N) {
    int i = blockIdx.x * blockDim.x + threadIdx.x;
    if (i >= N) return;
    int o = offs[i] + bsums[i >> 8];
    offs[i] = o;
    cursor[i] = o;
    dinv[i] = rsqrtf((float)(counts[i] + 1));  // +1 self-loop, always >= 1
}

__global__ void scatter_kernel(const int* __restrict__ src, const int* __restrict__ dst,
                               int* __restrict__ cursor, int* __restrict__ csr_src, int E) {
    int e = blockIdx.x * blockDim.x + threadIdx.x;
    if (e >= E) return;
    int p = atomicAdd(&cursor[dst[e]], 1);
    csr_src[p] = src[e];
}

// xwd = (x @ W1) * dinv[node]
__global__ void gemm1_kernel(const float* __restrict__ x, const float* __restrict__ W1,
                             const float* __restrict__ dinv, float* __restrict__ xwd, int N) {
    __shared__ float ws_[128 * 32];
    for (int i = threadIdx.x; i < 128 * 32; i += blockDim.x) ws_[i] = W1[i];
    __syncthreads();
    int node = blockIdx.x * blockDim.x + threadIdx.x;
    if (node >= N) return;
    float acc[32];
#pragma unroll
    for (int j = 0; j < 32; ++j) acc[j] = 0.0f;
    const float4* xr = (const float4*)(x + (size_t)node * 128);
#pragma unroll 4
    for (int k4 = 0; k4 < 32; ++k4) {
        float4 xv = xr[k4];
        const float* wk = ws_ + k4 * 128;
#pragma unroll
        for (int j4 = 0; j4 < 8; ++j4) {
            float4 w0 = *(const float4*)(wk + j4 * 4);
            float4 w1 = *(const float4*)(wk + 32 + j4 * 4);
            float4 w2 = *(const float4*)(wk + 64 + j4 * 4);
            float4 w3 = *(const float4*)(wk + 96 + j4 * 4);
            acc[j4 * 4 + 0] += xv.x * w0.x + xv.y * w1.x + xv.z * w2.x + xv.w * w3.x;
            acc[j4 * 4 + 1] += xv.x * w0.y + xv.y * w1.y + xv.z * w2.y + xv.w * w3.y;
            acc[j4 * 4 + 2] += xv.x * w0.z + xv.y * w1.z + xv.z * w2.z + xv.w * w3.z;
            acc[j4 * 4 + 3] += xv.x * w0.w + xv.y * w1.w + xv.z * w2.w + xv.w * w3.w;
        }
    }
    float d = dinv[node];
    float4* xp = (float4*)(xwd + (size_t)node * 32);
#pragma unroll
    for (int j4 = 0; j4 < 8; ++j4)
        xp[j4] = make_float4(acc[j4 * 4 + 0] * d, acc[j4 * 4 + 1] * d,
                             acc[j4 * 4 + 2] * d, acc[j4 * 4 + 3] * d);
}

// One wave per node: agg1[d] = dinv[d] * (xwd[d] + sum_{s in in(d)} xwd[s])
__global__ void agg32_kernel(const int* __restrict__ offs, const int* __restrict__ counts,
                             const int* __restrict__ csr_src, const float* __restrict__ dinv,
                             const float* __restrict__ xwd, float* __restrict__ agg, int N) {
    int wave = threadIdx.x >> 6;
    int lane = threadIdx.x & 63;
    int node = blockIdx.x * 4 + wave;
    if (node >= N) return;
    int f = lane & 31;
    int j = lane >> 5;  // 0..1 : two edges in flight per wave
    int off = offs[node];
    int deg = counts[node];
    float acc = (j == 0) ? xwd[(size_t)node * 32 + f] : 0.0f;
    for (int i = j; i < deg; i += 2) {
        int s = csr_src[off + i];
        acc += xwd[(size_t)s * 32 + f];
    }
    acc += __shfl_down(acc, 32, 64);
    if (j == 0) agg[(size_t)node * 32 + f] = acc * dinv[node];
}

// h2wd = (relu(agg1 + b1) @ W2) * dinv[node]
__global__ void gemm2_kernel(const float* __restrict__ agg1, const float* __restrict__ W2,
                             const float* __restrict__ b1, const float* __restrict__ dinv,
                             float* __restrict__ h2wd, int N) {
    __shared__ float ws_[32 * 16];
    __shared__ float bs_[32];
    for (int i = threadIdx.x; i < 32 * 16; i += blockDim.x) ws_[i] = W2[i];
    if (threadIdx.x < 32) bs_[threadIdx.x] = b1[threadIdx.x];
    __syncthreads();
    int node = blockIdx.x * blockDim.x + threadIdx.x;
    if (node >= N) return;
    float h[32];
    const float4* ar = (const float4*)(agg1 + (size_t)node * 32);
#pragma unroll
    for (int k4 = 0; k4 < 8; ++k4) {
        float4 v = ar[k4];
        h[k4 * 4 + 0] = fmaxf(v.x + bs_[k4 * 4 + 0], 0.0f);
        h[k4 * 4 + 1] = fmaxf(v.y + bs_[k4 * 4 + 1], 0.0f);
        h[k4 * 4 + 2] = fmaxf(v.z + bs_[k4 * 4 + 2], 0.0f);
        h[k4 * 4 + 3] = fmaxf(v.w + bs_[k4 * 4 + 3], 0.0f);
    }
    float acc[16];
#pragma unroll
    for (int j = 0; j < 16; ++j) acc[j] = 0.0f;
#pragma unroll
    for (int k = 0; k < 32; ++k) {
        float hv = h[k];
#pragma unroll
        for (int j4 = 0; j4 < 4; ++j4) {
            float4 w = *(const float4*)(ws_ + k * 16 + j4 * 4);
            acc[j4 * 4 + 0] += hv * w.x;
            acc[j4 * 4 + 1] += hv * w.y;
            acc[j4 * 4 + 2] += hv * w.z;
            acc[j4 * 4 + 3] += hv * w.w;
        }
    }
    float d = dinv[node];
    float4* hp = (float4*)(h2wd + (size_t)node * 16);
#pragma unroll
    for (int j4 = 0; j4 < 4; ++j4)
        hp[j4] = make_float4(acc[j4 * 4 + 0] * d, acc[j4 * 4 + 1] * d,
                             acc[j4 * 4 + 2] * d, acc[j4 * 4 + 3] * d);
}

// One wave per node, 16 feats: agg2[d] = dinv[d] * (h2wd[d] + sum h2wd[s])
__global__ void agg16_kernel(const int* __restrict__ offs, const int* __restrict__ counts,
                             const int* __restrict__ csr_src, const float* __restrict__ dinv,
                             const float* __restrict__ h2wd, float* __restrict__ agg, int N) {
    int wave = threadIdx.x >> 6;
    int lane = threadIdx.x & 63;
    int node = blockIdx.x * 4 + wave;
    if (node >= N) return;
    int f = lane & 15;
    int j = lane >> 4;  // 0..3 : four edges in flight per wave
    int off = offs[node];
    int deg = counts[node];
    float acc = (j == 0) ? h2wd[(size_t)node * 16 + f] : 0.0f;
    for (int i = j; i < deg; i += 4) {
        int s = csr_src[off + i];
        acc += h2wd[(size_t)s * 16 + f];
    }
    acc += __shfl_down(acc, 32, 64);
    acc += __shfl_down(acc, 16, 64);
    if (j == 0) agg[(size_t)node * 16 + f] = acc * dinv[node];
}

// out = relu(agg2 + b2) @ Wf + bf
__global__ void final_kernel(const float* __restrict__ agg2, const float* __restrict__ b2,
                             const float* __restrict__ Wf, const float* __restrict__ bf,
                             float* __restrict__ out, int N) {
    int i = blockIdx.x * blockDim.x + threadIdx.x;
    if (i >= N) return;
    const float4* ar = (const float4*)(agg2 + (size_t)i * 16);
    float acc = bf[0];
#pragma unroll
    for (int j4 = 0; j4 < 4; ++j4) {
        float4 v = ar[j4];
        acc += fmaxf(v.x + b2[j4 * 4 + 0], 0.0f) * Wf[j4 * 4 + 0];
        acc += fmaxf(v.y + b2[j4 * 4 + 1], 0.0f) * Wf[j4 * 4 + 1];
        acc += fmaxf(v.z + b2[j4 * 4 + 2], 0.0f) * Wf[j4 * 4 + 2];
        acc += fmaxf(v.w + b2[j4 * 4 + 3], 0.0f) * Wf[j4 * 4 + 3];
    }
    out[i] = acc;
}

extern "C" void kernel_launch(void* const* d_in, const int* in_sizes, int n_in,
                              void* d_out, int out_size, void* d_ws, size_t ws_size,
                              hipStream_t stream) {
    const float* x  = (const float*)d_in[0];
    const int*   ei = (const int*)d_in[1];
    const float* W1 = (const float*)d_in[2];
    const float* b1 = (const float*)d_in[3];
    const float* W2 = (const float*)d_in[4];
    const float* b2 = (const float*)d_in[5];
    const float* Wf = (const float*)d_in[6];
    const float* bf = (const float*)d_in[7];

    int N = in_sizes[0] / 128;
    int E = in_sizes[1] / 2;
    const int* src = ei;       // edge_index[0]
    const int* dst = ei + E;   // edge_index[1]

    // Workspace layout
    size_t Np = ((size_t)N + 3) & ~(size_t)3;  // float4 alignment for feature rows
    size_t Ep = ((size_t)E + 3) & ~(size_t)3;
    int* wsI      = (int*)d_ws;
    int* counts   = wsI;               // N
    int* offs     = counts + Np;       // N
    int* cursor   = offs + Np;         // N
    int* bsums    = cursor + Np;       // 512
    int* csr_src  = bsums + 512;       // E
    float* dinv   = (float*)(csr_src + Ep);   // N
    float* xwd    = dinv + Np;         // 32*N
    float* agg1   = xwd + 32 * Np;     // 32*N
    float* h2wd   = agg1 + 32 * Np;    // 16*N
    float* agg2   = h2wd + 16 * Np;    // 16*N
    float* out    = (float*)d_out;

    int nbN = (N + TPB - 1) / TPB;
    int nbE = (E + TPB - 1) / TPB;
    int nbW = (N + 3) / 4;  // one wave (of 4/block) per node

    zero_counts_kernel<<<nbN, TPB, 0, stream>>>(counts, N);
    count_kernel<<<nbE, TPB, 0, stream>>>(dst, counts, E);
    scan_block_kernel<<<nbN, TPB, 0, stream>>>(counts, offs, bsums, N);
    scan_sums_kernel<<<1, 512, 0, stream>>>(bsums, nbN);
    finalize_kernel<<<nbN, TPB, 0, stream>>>(counts, offs, bsums, cursor, dinv, N);
    scatter_kernel<<<nbE, TPB, 0, stream>>>(src, dst, cursor, csr_src, E);
    gemm1_kernel<<<nbN, TPB, 0, stream>>>(x, W1, dinv, xwd, N);
    agg32_kernel<<<nbW, TPB, 0, stream>>>(offs, counts, csr_src, dinv, xwd, agg1, N);
    gemm2_kernel<<<nbN, TPB, 0, stream>>>(agg1, W2, b1, dinv, h2wd, N);
    agg16_kernel<<<nbW, TPB, 0, stream>>>(offs, counts, csr_src, dinv, h2wd, agg2, N);
    final_kernel<<<nbN, TPB, 0, stream>>>(agg2, b2, Wf, bf, out, N);
}